// Round 7
// baseline (375.568 us; speedup 1.0000x reference)
//
#include <hip/hip_runtime.h>

typedef unsigned short u16;
typedef unsigned int   u32;
typedef __bf16 bf16x8 __attribute__((ext_vector_type(8)));
typedef float  f32x4  __attribute__((ext_vector_type(4)));
typedef u16    u16x4  __attribute__((ext_vector_type(4)));

#define DEV __device__ __forceinline__

DEV u16 f2bf(float f) {
    u32 u = __builtin_bit_cast(u32, f);
    u = (u + 0x7fffu + ((u >> 16) & 1u)) >> 16;
    return (u16)u;
}

DEV void gload16(const void* g, void* l) {
    __builtin_amdgcn_global_load_lds((const __attribute__((address_space(1))) u32*)g,
                                     (__attribute__((address_space(3))) u32*)l, 16, 0, 0);
}

DEV void vmw(int n) {  // counted vmcnt wait
    switch (n) {
        case 0:  asm volatile("s_waitcnt vmcnt(0)" ::: "memory"); break;
        case 4:  asm volatile("s_waitcnt vmcnt(4)" ::: "memory"); break;
        default: asm volatile("s_waitcnt vmcnt(8)" ::: "memory"); break;
    }
}

// ---------------- merged prep: x->bf16 | E/F transpose | W transposes ----------------
__global__ __launch_bounds__(256) void k_prep(const float* __restrict__ x,
                                              const float* __restrict__ wq, const float* __restrict__ wk,
                                              const float* __restrict__ wv, const float* __restrict__ wo,
                                              const float* __restrict__ E, const float* __restrict__ F,
                                              u16* __restrict__ xb, u16* __restrict__ wcatT, u16* __restrict__ woT,
                                              u16* __restrict__ Et, u16* __restrict__ Ft) {
    __shared__ u16 tile[64][68];   // 136B row stride: 8B-aligned quads, odd dword stride
    const int t = threadIdx.x;
    const int bid = blockIdx.x;
    if (bid < 16384) {                       // x fp32 -> bf16
        int i = (bid * 256 + t) * 4;
        float4 v = *(const float4*)(x + i);
        u16x4 o;
        o[0] = f2bf(v.x); o[1] = f2bf(v.y); o[2] = f2bf(v.z); o[3] = f2bf(v.w);
        *(u16x4*)(xb + i) = o;
    } else if (bid < 20480) {                // E/F [h][n][r] -> [h][r][n] bf16, 64x64 tiles
        const int b2 = bid - 16384;
        const int rt = b2 & 3, ntl = (b2 >> 2) & 63, h = (b2 >> 8) & 7, which = b2 >> 11;
        const float* src = (which ? F : E) + (size_t)h * 4096 * 256;
        u16* dst = (which ? Ft : Et) + (size_t)h * 256 * 4096;
        const int n0 = ntl * 64, r0 = rt * 64;
#pragma unroll
        for (int it = 0; it < 4; ++it) {
            const int idx = t + it * 256;
            const int nl = idx >> 4, rq = (idx & 15) * 4;
            float4 v = *(const float4*)(src + (size_t)(n0 + nl) * 256 + r0 + rq);
            tile[rq + 0][nl] = f2bf(v.x);
            tile[rq + 1][nl] = f2bf(v.y);
            tile[rq + 2][nl] = f2bf(v.z);
            tile[rq + 3][nl] = f2bf(v.w);
        }
        __syncthreads();
#pragma unroll
        for (int it = 0; it < 4; ++it) {
            const int idx = t + it * 256;
            const int rl = idx >> 4, nq = (idx & 15) * 4;
            u16x4 vv = *(const u16x4*)&tile[rl][nq];
            *(u16x4*)(dst + (size_t)(r0 + rl) * 4096 + n0 + nq) = vv;
        }
    } else {                                 // W transposes, 64x64 tiles
        const int b2 = bid - 20480;
        const int mi = b2 >> 6, tix = b2 & 63;
        const int jt = tix & 7, kt = tix >> 3;
        const float* w = (mi == 0) ? wq : (mi == 1) ? wk : (mi == 2) ? wv : wo;
        u16* dst = (mi < 3) ? (wcatT + mi * 262144) : woT;
#pragma unroll
        for (int it = 0; it < 4; ++it) {
            const int idx = t + it * 256;
            const int kl = idx >> 4, jq = (idx & 15) * 4;
            float4 v = *(const float4*)(w + (size_t)(kt * 64 + kl) * 512 + jt * 64 + jq);
            tile[jq + 0][kl] = f2bf(v.x);
            tile[jq + 1][kl] = f2bf(v.y);
            tile[jq + 2][kl] = f2bf(v.z);
            tile[jq + 3][kl] = f2bf(v.w);
        }
        __syncthreads();
#pragma unroll
        for (int it = 0; it < 4; ++it) {
            const int idx = t + it * 256;
            const int jl = idx >> 4, kq = (idx & 15) * 4;
            u16x4 vv = *(const u16x4*)&tile[jl][kq];
            *(u16x4*)(dst + (size_t)(jt * 64 + jl) * 512 + kt * 64 + kq) = vv;
        }
    }
}

// ---------------- 16-phase 256x256 bf16 GEMM: C[M][N] = A[M][K] * B^T[N][K] ----------------
// 512 thr / 8 waves (2x4), per-wave C = 128x64. Phase = one K-half (BK/2=32): 32 MFMA,
// 12 ds_read_b128, stage one A+B half-pair (4 gload_lds). Ring of 4 slots per operand.
// vmcnt: steady 8 (2 pairs in flight), tail 4 -> 0.
template <int MODE>
__global__ __launch_bounds__(512, 2) void k_gemm8(const u16* __restrict__ A, const u16* __restrict__ Bm,
                                                  u16* __restrict__ Qo, u16* __restrict__ Kt, u16* __restrict__ Vt,
                                                  float* __restrict__ Of, const float* __restrict__ bias,
                                                  int M, int N, int K) {
    __shared__ __attribute__((aligned(16))) char smem[131072];
    const int tid = threadIdx.x;
    const int lane = tid & 63, w = tid >> 6;
    const int wr = w >> 2, wcn = w & 3;
    const int g = lane >> 4, l16 = lane & 15;
    const int nbm = M >> 8;
    const int bnc = N >> 8;
    const int bandw = nbm >> 3;               // bm tiles per XCD
    const int bid = (int)blockIdx.x;
    const int xcd = bid & 7, loc = bid >> 3;
    const int bm = xcd * bandw + loc / bnc;   // XCD-fixed band, bn-fast
    const int bn = loc % bnc;
    const int m0 = bm << 8, n0 = bn << 8;
    const int NP = K >> 5;                    // phases = 2*NT

    auto stage_pair = [&](int P) {            // stage A+B half-tiles for pair P
        const int kt = P >> 1, kh = P & 1;
        const int slot = P & 3;
#pragma unroll
        for (int isB = 0; isB < 2; ++isB) {
            const u16* src = isB ? Bm : A;
            const int r0 = isB ? n0 : m0;
            char* base = smem + isB * 65536 + slot * 16384;
#pragma unroll
            for (int j = 0; j < 2; ++j) {
                const int off = j * 8192 + tid * 16;
                const int row = off >> 6, c = (off >> 4) & 3;
                const int sc = c ^ ((row >> 1) & 3);   // pre-swizzled source
                gload16(src + (size_t)(r0 + row) * K + kt * 64 + kh * 32 + sc * 8, base + off);
            }
        }
    };

    stage_pair(0); stage_pair(1); stage_pair(2);
    vmw(8);                                   // pair 0 landed
    __builtin_amdgcn_sched_barrier(0);
    __builtin_amdgcn_s_barrier();

    f32x4 acc[8][4] = {};
    for (int P = 0; P < NP; ++P) {
        const int slot = P & 3;
        char* abase = smem + slot * 16384;
        char* bbase = smem + 65536 + slot * 16384;
        bf16x8 av[8], bv[4];
#pragma unroll
        for (int m = 0; m < 8; ++m) {
            const int row = wr * 128 + m * 16 + l16;
            const int c = g ^ ((row >> 1) & 3);
            av[m] = *(const bf16x8*)(abase + row * 64 + c * 16);
        }
#pragma unroll
        for (int n = 0; n < 4; ++n) {
            const int col = wcn * 64 + n * 16 + l16;
            const int c = g ^ ((col >> 1) & 3);
            bv[n] = *(const bf16x8*)(bbase + col * 64 + c * 16);
        }
        if (P + 3 < NP) stage_pair(P + 3);
        __builtin_amdgcn_s_setprio(1);
#pragma unroll
        for (int m = 0; m < 8; ++m)
#pragma unroll
            for (int n = 0; n < 4; ++n)
                acc[m][n] = __builtin_amdgcn_mfma_f32_16x16x32_bf16(av[m], bv[n], acc[m][n], 0, 0, 0);
        __builtin_amdgcn_s_setprio(0);
        if (P < NP - 1) {
            vmw(P < NP - 3 ? 8 : (P == NP - 3 ? 4 : 0));
            __builtin_amdgcn_sched_barrier(0);
            __builtin_amdgcn_s_barrier();
        }
    }

    if (MODE == 0) {
        if (n0 < 512) {  // Q section: natural [32768][512]
#pragma unroll
            for (int m = 0; m < 8; ++m)
#pragma unroll
                for (int jn = 0; jn < 4; ++jn) {
                    const int col = n0 + wcn * 64 + jn * 16 + l16;
#pragma unroll
                    for (int i = 0; i < 4; ++i) {
                        const int row = m0 + wr * 128 + m * 16 + g * 4 + i;
                        Qo[(size_t)row * 512 + col] = f2bf(acc[m][jn][i]);
                    }
                }
        } else {         // K/V: transposed per head [b,h,d,n]
            u16* dst = (n0 < 1024) ? Kt : Vt;
#pragma unroll
            for (int m = 0; m < 8; ++m)
#pragma unroll
                for (int jn = 0; jn < 4; ++jn) {
                    const int col = (n0 + wcn * 64 + jn * 16 + l16) & 511;
                    const int h = col >> 6, d = col & 63;
                    const int rowb = m0 + wr * 128 + m * 16 + g * 4;
                    const int b = rowb >> 12, nn = rowb & 4095;
                    u16x4 pk;
#pragma unroll
                    for (int i = 0; i < 4; ++i) pk[i] = f2bf(acc[m][jn][i]);
                    *(u16x4*)(dst + ((size_t)((b * 8 + h) * 64 + d)) * 4096 + nn) = pk;
                }
        }
    } else {
#pragma unroll
        for (int m = 0; m < 8; ++m)
#pragma unroll
            for (int jn = 0; jn < 4; ++jn) {
                const int col = n0 + wcn * 64 + jn * 16 + l16;
                const float bb = bias[col];
#pragma unroll
                for (int i = 0; i < 4; ++i) {
                    const int row = m0 + wr * 128 + m * 16 + g * 4 + i;
                    Of[(size_t)row * N + col] = acc[m][jn][i] + bb;
                }
            }
    }
}

// ---------------- Linformer projections, split-K x4 (unchanged) ----------------
__global__ __launch_bounds__(256) void k_proj(const u16* __restrict__ Et, const u16* __restrict__ Ft,
                                              const u16* __restrict__ Kt, const u16* __restrict__ Vt,
                                              float* __restrict__ pbuf) {
    __shared__ __attribute__((aligned(16))) char smem[24576];
    const int tid = threadIdx.x;
    const int lane = tid & 63, wid = tid >> 6;
    const int wr = wid >> 1, wc = wid & 1;
    const int g = lane >> 4, l16 = lane & 15;
    const int bid = blockIdx.x;
    const int sp = bid >> 8, rest = bid & 255;
    const int mt = rest & 1, which = (rest >> 1) & 1, bh = rest >> 2;
    const int h = bh & 7;
    const u16* Ap = (which ? Ft : Et) + (size_t)h * 256 * 4096 + (size_t)mt * 128 * 4096;
    const u16* Bp = (which ? Vt : Kt) + (size_t)bh * 64 * 4096;

    f32x4 acc[4][2] = {};

    const int kbeg = sp * 1024;
    for (int k0 = kbeg; k0 < kbeg + 1024; k0 += 64) {
#pragma unroll
        for (int c = 0; c < 4; ++c) {
            const int off = c * 4096 + tid * 16;
            const int row = off >> 7;
            const int sc = ((off >> 4) & 7) ^ (row & 7);
            gload16(Ap + (size_t)row * 4096 + (k0 + sc * 8), smem + off);
            if (c < 2)
                gload16(Bp + (size_t)row * 4096 + (k0 + sc * 8), smem + 16384 + off);
        }
        __syncthreads();
#pragma unroll
        for (int kk = 0; kk < 64; kk += 32) {
            bf16x8 av[4], bv[2];
#pragma unroll
            for (int m = 0; m < 4; ++m) {
                const int r = wr * 64 + m * 16 + l16;
                av[m] = *(const bf16x8*)(smem + r * 128 + ((kk * 2 + g * 16) ^ ((r & 7) << 4)));
            }
#pragma unroll
            for (int n = 0; n < 2; ++n) {
                const int r = wc * 32 + n * 16 + l16;
                bv[n] = *(const bf16x8*)(smem + 16384 + r * 128 + ((kk * 2 + g * 16) ^ ((r & 7) << 4)));
            }
            __builtin_amdgcn_s_setprio(1);
#pragma unroll
            for (int m = 0; m < 4; ++m)
#pragma unroll
                for (int n = 0; n < 2; ++n)
                    acc[m][n] = __builtin_amdgcn_mfma_f32_16x16x32_bf16(av[m], bv[n], acc[m][n], 0, 0, 0);
            __builtin_amdgcn_s_setprio(0);
        }
        __syncthreads();
    }

    float* pb = pbuf + ((size_t)(sp * 2 + which) * 64 + bh) * 16384;
    if (which == 0) {
#pragma unroll
        for (int m = 0; m < 4; ++m)
#pragma unroll
            for (int n = 0; n < 2; ++n) {
                const int d = wc * 32 + n * 16 + l16;
#pragma unroll
                for (int i = 0; i < 4; ++i) {
                    const int rg = mt * 128 + wr * 64 + m * 16 + g * 4 + i;
                    pb[rg * 64 + d] = acc[m][n][i];
                }
            }
    } else {
#pragma unroll
        for (int m = 0; m < 4; ++m)
#pragma unroll
            for (int n = 0; n < 2; ++n) {
                const int d = wc * 32 + n * 16 + l16;
                const int r4 = mt * 128 + wr * 64 + m * 16 + g * 4;
                *(f32x4*)(pb + d * 256 + r4) = acc[m][n];
            }
    }
}

__global__ __launch_bounds__(256) void k_preduce(const float* __restrict__ pbuf, u16* __restrict__ outkv) {
    const int o = ((int)blockIdx.x * 256 + (int)threadIdx.x) * 4;
    f32x4 s = *(const f32x4*)(pbuf + o);
    s += *(const f32x4*)(pbuf + 2097152 + o);
    s += *(const f32x4*)(pbuf + 4194304 + o);
    s += *(const f32x4*)(pbuf + 6291456 + o);
    u16x4 r;
#pragma unroll
    for (int i = 0; i < 4; ++i) r[i] = f2bf(s[i]);
    *(u16x4*)(outkv + o) = r;
}

// ---------------- fused scores + softmax + PV: 8 waves, 512 rows/block, 4 passes ----------------
// LDS: kp [256][64] swz @0 (32K), vpT [64][256] swz @32K (32K), P per-wave @64K (64K).
// Stage once; passes are barrier-free (P bounce is same-wave ordered). Q prefetched.
__global__ __launch_bounds__(512) void k_flash(const u16* __restrict__ Q, const u16* __restrict__ kp,
                                               const u16* __restrict__ vpT, u16* __restrict__ ctx) {
    __shared__ __attribute__((aligned(16))) char smem[131072];
    const int tid = threadIdx.x;
    const int lane = tid & 63, w = tid >> 6;
    const int g = lane >> 4, l16 = lane & 15;
    const int bid = blockIdx.x;
    const int seg = bid & 7, bh = bid >> 3;
    const int b = bh >> 3, h = bh & 7;
    const int n0 = seg * 512;

#pragma unroll
    for (int c = 0; c < 4; ++c) {
        const int off = c * 8192 + tid * 16;
        {
            const int row = off >> 7;
            const int sc = ((off >> 4) & 7) ^ (row & 7);
            gload16(kp + (size_t)bh * 16384 + row * 64 + sc * 8, smem + off);
        }
        {
            const int row = off >> 9;
            const int sc = ((off >> 4) & 31) ^ (row & 7);
            gload16(vpT + (size_t)bh * 16384 + row * 256 + sc * 8, smem + 32768 + off);
        }
    }
    const size_t qrow0 = (size_t)(b * 4096 + n0 + w * 16 + l16) * 512 + h * 64 + g * 8;
    bf16x8 qf0 = *(const bf16x8*)(Q + qrow0);
    bf16x8 qf1 = *(const bf16x8*)(Q + qrow0 + 32);
    __syncthreads();

    const int pbase = 65536 + w * 8192;
    for (int qp = 0; qp < 4; ++qp) {
        // scores: S[n][r], 16 r-tiles
        f32x4 s[16];
        __builtin_amdgcn_s_setprio(1);
#pragma unroll
        for (int rt = 0; rt < 16; ++rt) {
            const int r = rt * 16 + l16;
            const int sw = (r & 7) << 4;
            bf16x8 kv0 = *(const bf16x8*)(smem + r * 128 + ((g * 16) ^ sw));
            bf16x8 kv1 = *(const bf16x8*)(smem + r * 128 + ((64 + g * 16) ^ sw));
            f32x4 z = {0.f, 0.f, 0.f, 0.f};
            z = __builtin_amdgcn_mfma_f32_16x16x32_bf16(qf0, kv0, z, 0, 0, 0);
            z = __builtin_amdgcn_mfma_f32_16x16x32_bf16(qf1, kv1, z, 0, 0, 0);
            s[rt] = z;
        }
        __builtin_amdgcn_s_setprio(0);

        // prefetch next pass's Q (latency hidden under softmax+PV)
        if (qp < 3) {
            const size_t qn = qrow0 + (size_t)(qp + 1) * 128 * 512;
            qf0 = *(const bf16x8*)(Q + qn);
            qf1 = *(const bf16x8*)(Q + qn + 32);
        }

        float mx[4] = {-1e30f, -1e30f, -1e30f, -1e30f};
#pragma unroll
        for (int rt = 0; rt < 16; ++rt)
#pragma unroll
            for (int i = 0; i < 4; ++i) {
                s[rt][i] *= 0.125f;
                mx[i] = fmaxf(mx[i], s[rt][i]);
            }
#pragma unroll
        for (int i = 0; i < 4; ++i) {
            mx[i] = fmaxf(mx[i], __shfl_xor(mx[i], 1));
            mx[i] = fmaxf(mx[i], __shfl_xor(mx[i], 2));
            mx[i] = fmaxf(mx[i], __shfl_xor(mx[i], 4));
            mx[i] = fmaxf(mx[i], __shfl_xor(mx[i], 8));
        }
        float sm[4] = {0.f, 0.f, 0.f, 0.f};
#pragma unroll
        for (int rt = 0; rt < 16; ++rt)
#pragma unroll
            for (int i = 0; i < 4; ++i) {
                float e = __expf(s[rt][i] - mx[i]);
                s[rt][i] = e;
                sm[i] += e;
            }
#pragma unroll
        for (int i = 0; i < 4; ++i) {
            sm[i] += __shfl_xor(sm[i], 1);
            sm[i] += __shfl_xor(sm[i], 2);
            sm[i] += __shfl_xor(sm[i], 4);
            sm[i] += __shfl_xor(sm[i], 8);
        }

        // unnormalized P (bf16) to per-wave region [16][256], swizzled (same-wave ordered)
#pragma unroll
        for (int rt = 0; rt < 16; ++rt)
#pragma unroll
            for (int i = 0; i < 4; ++i) {
                const int nrow = g * 4 + i;
                const int byte = pbase + nrow * 512 + ((rt * 32 + l16 * 2) ^ ((nrow & 7) << 4));
                *(u16*)(smem + byte) = f2bf(s[rt][i]);
            }
        bf16x8 af[8];
#pragma unroll
        for (int ks = 0; ks < 8; ++ks) {
            const int byte = pbase + l16 * 512 + ((ks * 64 + g * 16) ^ ((l16 & 7) << 4));
            af[ks] = *(const bf16x8*)(smem + byte);
        }
        f32x4 o[4] = {};
        __builtin_amdgcn_s_setprio(1);
#pragma unroll
        for (int dt = 0; dt < 4; ++dt)
#pragma unroll
            for (int ks = 0; ks < 8; ++ks) {
                const int row = dt * 16 + l16;
                const int byte = 32768 + row * 512 + ((ks * 64 + g * 16) ^ ((row & 7) << 4));
                bf16x8 bv = *(const bf16x8*)(smem + byte);
                o[dt] = __builtin_amdgcn_mfma_f32_16x16x32_bf16(af[ks], bv, o[dt], 0, 0, 0);
            }
        __builtin_amdgcn_s_setprio(0);
        float rinv[4];
#pragma unroll
        for (int i = 0; i < 4; ++i) rinv[i] = 1.0f / sm[i];
#pragma unroll
        for (int dt = 0; dt < 4; ++dt)
#pragma unroll
            for (int i = 0; i < 4; ++i) {
                const int row = b * 4096 + n0 + qp * 128 + w * 16 + g * 4 + i;
                const int col = h * 64 + dt * 16 + l16;
                ctx[(size_t)row * 512 + col] = f2bf(o[dt][i] * rinv[i]);
            }
    }
}

// ---------------- host launch ----------------

extern "C" void kernel_launch(void* const* d_in, const int* in_sizes, int n_in,
                              void* d_out, int out_size, void* d_ws, size_t ws_size,
                              hipStream_t stream) {
    const float* x  = (const float*)d_in[0];
    const float* wq = (const float*)d_in[1];
    const float* wk = (const float*)d_in[2];
    const float* wv = (const float*)d_in[3];
    const float* E  = (const float*)d_in[4];
    const float* F  = (const float*)d_in[5];
    const float* wo = (const float*)d_in[6];
    const float* bo = (const float*)d_in[7];
    float* out = (float*)d_out;
    u16* ws = (u16*)d_ws;

    u16* xb    = ws;                 // x bf16 -> proj partials (f32) -> ctx
    u16* Qm    = ws + 16777216;
    u16* Kt    = ws + 33554432;      // [b,h,d,n]
    u16* Vt    = ws + 50331648;      // [b,h,d,n]
    u16* Et    = ws + 67108864;      // [h,r,n]
    u16* Ft    = ws + 75497472;
    u16* wcatT = ws + 83886080;
    u16* woT   = ws + 84672512;
    u16* kpB   = ws + 84934656;      // [bh,r,d] (kpB/vpT contiguous)
    u16* vpT   = ws + 85983232;      // [bh,d,r]
    float* pbuf = (float*)xb;
    u16* ctx   = xb;

    k_prep<<<20736, 256, 0, stream>>>(x, wq, wk, wv, wo, E, F, xb, wcatT, woT, Et, Ft);
    k_gemm8<0><<<768, 512, 0, stream>>>(xb, wcatT, Qm, Kt, Vt, nullptr, nullptr, 32768, 1536, 512);
    k_proj<<<1024, 256, 0, stream>>>(Et, Ft, Kt, Vt, pbuf);
    k_preduce<<<2048, 256, 0, stream>>>(pbuf, kpB);
    k_flash<<<512, 512, 0, stream>>>(Qm, kpB, vpT, ctx);
    k_gemm8<1><<<256, 512, 0, stream>>>(ctx, woT, nullptr, nullptr, nullptr, out, bo, 32768, 512, 512);
}